// Round 14
// baseline (1333.378 us; speedup 1.0000x reference)
//
#include <hip/hip_runtime.h>

#define D_IN 2312
#define HID  800
#define NCLS 10
#define BATCH 128
#define TSTEPS 300
#define WIN  50

#define MT 64                              // block tile rows (2 waves x 32)
#define NT 32
#define BKK 16
#define NTM 100                            // 6400/64
#define NTN 25                             // 800/32, exact
#define GEMM_BLOCKS (NTM * NTN)            // 2500 two-wave tiles
#define BLK 128
#define RPASTE 960                         // paste blocks (128 thr each)
#define PASTE_BASE (GEMM_BLOCKS + BATCH)   // 2628
#define NB (PASTE_BASE + RPASTE)           // 3588
#define TOTQ (BATCH * D_IN * (TSTEPS / 4)) // 22,195,200 float4s of X
#define P_BYTES (6400 * 800 * 4)           // 20,480,000

// ---------------------------------------------------------------------------
// DPP full-wave sum (proven round 6): VALU-speed cross-lane, no LDS pipe.
// ---------------------------------------------------------------------------
template <int CTRL>
__device__ __forceinline__ float dpp_add(float s) {
  return s + __int_as_float(__builtin_amdgcn_update_dpp(
      0, __float_as_int(s), CTRL, 0xf, 0xf, true));
}
__device__ __forceinline__ float wave_sum(float s) {
  s = dpp_add<0x111>(s);   // row_shr:1
  s = dpp_add<0x112>(s);   // row_shr:2
  s = dpp_add<0x114>(s);   // row_shr:4
  s = dpp_add<0x118>(s);   // row_shr:8   -> lane15 of each row = row sum
  s = dpp_add<0x142>(s);   // row_bcast:15 -> lane31 = r0+r1, lane63 = r2+r3
  s = dpp_add<0x143>(s);   // row_bcast:31 -> lane63 = total
  return __int_as_float(__builtin_amdgcn_readlane(__float_as_int(s), 63));
}

// ===========================================================================
// FUSED single-launch kernel: gemm + recur (spin-wait on per-m-tile flags) +
// paste. Overlap: recur for batch b needs only m-tiles floor(50b/64) and
// floor((50b+49)/64); gemm blocks release-fence + atomicAdd cnt[mt] after
// their C-write; recur blocks acquire after observing cnt[mt]==25 (G16
// device-scope atomics/fences pattern). Deadlock-free: gemm/paste never
// wait; 128 spinners can't exhaust block slots; paste retires -> gemm drains.
// VGPR coupling controlled: recur reads W2 from GLOBAL (off the serial
// cs-chain, 32KB L1-resident, same values + fmaf order -> identical FP) so
// the kernel-wide VGPR alloc stays ~120 and gemm occupancy is preserved.
// gemm path = EXACT R12 (proven 357us, 48 VGPR, FETCH 181 MB).
// ===========================================================================
__global__ __launch_bounds__(BLK) void fused_all(
    const float* __restrict__ inp,   // [B][D_IN][WIN]
    const float* __restrict__ W1,    // [HID][D_IN]
    const int*   __restrict__ idx,   // [B]
    float*       __restrict__ P,     // [6400][HID]
    const float* __restrict__ W2,    // [NCLS][HID]
    const float* __restrict__ b2,    // [NCLS]
    const float* __restrict__ Wc,    // [HID+4]
    const float* __restrict__ bc,    // [1]
    const float* __restrict__ b1,    // [HID]
    float*       __restrict__ out,   // [B][NCLS]
    float*       __restrict__ outX,  // [B][D_IN][T]
    int*         __restrict__ cnt)   // [NTM] ready counters (pre-zeroed)
{
  __shared__ float As[BKK][MT];       // 4 KB
  __shared__ float Bs[BKK][NT + 4];   // 2.25 KB

  int t   = threadIdx.x;
  int bxg = blockIdx.x;

  if (bxg < GEMM_BLOCKS) {
    // ---------------- GEMM role (exact R12) ----------------
    // bijective XCD swizzle: 2500 = 8*312 + 4 (validated R10/R11)
    int xcd = bxg & 7;
    int jj  = bxg >> 3;
    const int q8 = GEMM_BLOCKS >> 3;      // 312
    const int r8 = GEMM_BLOCKS & 7;       // 4
    int bx = (xcd < r8 ? xcd * (q8 + 1) : r8 * (q8 + 1) + (xcd - r8) * q8) + jj;

    int mt = bx / NTN;                 // 25 logical blocks share m-tile
    int nt = bx - mt * NTN;
    int m0 = mt * MT, n0 = nt * NT;

    int am = t & 63;
    int ah = t >> 6;                   // 0..1 -> k-half (== wave id)
    int r  = m0 + am;
    int bb = r / 50, ss = r - bb * 50;
    const float* aptr = inp + (size_t)bb * (D_IN * WIN) + ss;   // + k*WIN

    int bn = t >> 4;                   // 0..7
    int bk = t & 15;                   // 0..15

    int l  = t & 63;
    int lm = l & 7;
    int ln = l >> 3;
    int tm = ah * 32 + lm * 4;
    int tn = ln * 4;

    float aN[8], bN[4];
#pragma unroll
    for (int q = 0; q < 8; ++q) aN[q] = aptr[(ah * 8 + q) * WIN];
#pragma unroll
    for (int p = 0; p < 4; ++p)
      bN[p] = W1[(size_t)(n0 + bn + 8 * p) * D_IN + bk];

    float acc[4][4] = {};

    for (int k0 = 0; k0 < D_IN; k0 += BKK) {   // 145 slabs, last partial
#pragma unroll
      for (int q = 0; q < 8; ++q) As[ah * 8 + q][am] = aN[q];
#pragma unroll
      for (int p = 0; p < 4; ++p) Bs[bk][bn + 8 * p] = bN[p];
      __syncthreads();

      int kn0 = k0 + BKK;
      if (kn0 + BKK <= D_IN) {
#pragma unroll
        for (int q = 0; q < 8; ++q) aN[q] = aptr[(kn0 + ah * 8 + q) * WIN];
#pragma unroll
        for (int p = 0; p < 4; ++p)
          bN[p] = W1[(size_t)(n0 + bn + 8 * p) * D_IN + kn0 + bk];
      } else if (kn0 < D_IN) {
#pragma unroll
        for (int q = 0; q < 8; ++q) {
          int kk = kn0 + ah * 8 + q;
          aN[q] = (kk < D_IN) ? aptr[kk * WIN] : 0.f;
        }
#pragma unroll
        for (int p = 0; p < 4; ++p) {
          int kk = kn0 + bk;
          bN[p] = (kk < D_IN) ? W1[(size_t)(n0 + bn + 8 * p) * D_IN + kk] : 0.f;
        }
      }

#pragma unroll
      for (int kk = 0; kk < BKK; ++kk) {
        float4 A0 = *(const float4*)&As[kk][tm];
        float4 B0 = *(const float4*)&Bs[kk][tn];
        float av[4] = {A0.x, A0.y, A0.z, A0.w};
        float bv[4] = {B0.x, B0.y, B0.z, B0.w};
#pragma unroll
        for (int i = 0; i < 4; ++i)
#pragma unroll
          for (int j = 0; j < 4; ++j)
            acc[i][j] += av[i] * bv[j];
      }
      __syncthreads();
    }

#pragma unroll
    for (int i = 0; i < 4; ++i) {
      int row = m0 + tm + i;
      *(float4*)&P[(size_t)row * HID + n0 + tn] =
          make_float4(acc[i][0], acc[i][1], acc[i][2], acc[i][3]);
    }
    // signal: all block stores are waited at the barrier, then release.
    __syncthreads();
    if (t == 0) {
      __threadfence();                 // release (L2 writeback, device scope)
      atomicAdd(&cnt[mt], 1);
    }
    return;
  }

  if (bxg < PASTE_BASE) {
    // ---------------- RECUR role (v7 arithmetic, W2 from global) ----------
    if (t >= 64) return;               // single-wave role
    int L = t;
    int b = bxg - GEMM_BLOCKS;

    // P-independent setup BEFORE the spin (hides it under gemm)
    int myidx = idx[b];
    const float* Pb = P + (size_t)b * WIN * HID;

    float m[13], b1r[13], wcr[13];
    unsigned smask = 0;
#pragma unroll
    for (int rr = 0; rr < 13; ++rr) {
      int j = L + 64 * rr;
      bool ok = (j < HID);
      m[rr]   = 0.f;
      b1r[rr] = ok ? b1[j] : 0.f;
      wcr[rr] = ok ? Wc[j] : 0.f;
    }

    float cm = 0.f, cs = 0.f, bgt = 1.f;
    float bc0 = bc[0];
    float wf0 = Wc[HID], wf1 = Wc[HID + 1], wf2 = Wc[HID + 2], wf3 = Wc[HID + 3];

    float h2m[10], h2s[10], sum2[10], b2r[10];
#pragma unroll
    for (int c = 0; c < NCLS; ++c) { h2m[c] = 0.f; h2s[c] = 0.f; sum2[c] = 0.f; b2r[c] = b2[c]; }

    // wait for this batch's m-tiles (rows 50b .. 50b+49)
    int mt0 = (50 * b) >> 6;
    int mt1 = (50 * b + 49) >> 6;
    for (;;) {
      int v = __builtin_amdgcn_readfirstlane(atomicAdd(&cnt[mt0], 0));
      if (v >= NTN) break;
      __builtin_amdgcn_s_sleep(32);
    }
    if (mt1 != mt0) {
      for (;;) {
        int v = __builtin_amdgcn_readfirstlane(atomicAdd(&cnt[mt1], 0));
        if (v >= NTN) break;
        __builtin_amdgcn_s_sleep(32);
      }
    }
    __threadfence();                   // acquire (invalidate, device scope)

    // prefetch P row for step 0
    float cur[13];
    {
      unsigned w0 = (unsigned)(0 - myidx);
      if (w0 < (unsigned)WIN) {
        const float* Pr = Pb + (size_t)w0 * HID;
#pragma unroll
        for (int rr = 0; rr < 13; ++rr) {
          int j = L + 64 * rr;
          cur[rr] = (j < HID) ? Pr[j] : 0.f;
        }
      } else {
#pragma unroll
        for (int rr = 0; rr < 13; ++rr) cur[rr] = 0.f;
      }
    }

    for (int step = 0; step < TSTEPS; ++step) {
      float gate = (step == 0) ? 1.f : cs;

      float nxt[13];
      {
        unsigned wn = (unsigned)(step + 1 - myidx);
        if (wn < (unsigned)WIN) {
          const float* Pr = Pb + (size_t)wn * HID;
#pragma unroll
          for (int rr = 0; rr < 13; ++rr) {
            int j = L + 64 * rr;
            nxt[rr] = (j < HID) ? Pr[j] : 0.f;
          }
        } else {
#pragma unroll
          for (int rr = 0; rr < 13; ++rr) nxt[rr] = 0.f;
        }
      }

      unsigned nmask = 0;
#pragma unroll
      for (int rr = 0; rr < 13; ++rr) {
        float mprev = ((smask >> rr) & 1u) ? 0.f : m[rr] * 0.1f;
        float mv = mprev + cur[rr] * gate + b1r[rr];
        m[rr] = mv;
        nmask |= (mv > 0.5f) ? (1u << rr) : 0u;
      }
      smask = nmask;

      unsigned long long ball = __ballot(smask != 0u);

      float ctrl = 0.f;
      float dot[10];
#pragma unroll
      for (int c = 0; c < NCLS; ++c) dot[c] = 0.f;

      if (ball) {
        float cacc = 0.f;
#pragma unroll
        for (int rr = 0; rr < 13; ++rr) {
          float f = (float)((smask >> rr) & 1u);
          cacc = fmaf(f, wcr[rr], cacc);
        }
        ctrl = wave_sum(cacc);

        // h2 dots: W2 straight from global (L1-resident 32KB; off the
        // serial cs-chain; same values + fmaf order as w2r -> identical FP)
#pragma unroll
        for (int rr = 0; rr < 13; ++rr) {
          float f = (float)((smask >> rr) & 1u);
          int j = L + 64 * rr;
          bool ok = (j < HID);
#pragma unroll
          for (int c = 0; c < NCLS; ++c) {
            float w = ok ? W2[c * HID + j] : 0.f;
            dot[c] = fmaf(f, w, dot[c]);
          }
        }
#pragma unroll
        for (int c = 0; c < NCLS; ++c) dot[c] = wave_sum(dot[c]);
      }

      bgt += (cs == 1.f) ? 1.f : 0.f;
      float fq = wf0;
      if ((step & 1) == 0)   fq += wf1;
      if (step % 10 == 0)    fq += wf2;
      if (step % 100 == 0)   fq += wf3;
      float cv = (cs != 0.f ? 0.f : cm * 0.1f) + ctrl + fq + bc0;
      cm = cv;
      cs = (cv > 0.5f) ? 1.f : 0.f;

#pragma unroll
      for (int c = 0; c < NCLS; ++c) {
        float v = (h2s[c] != 0.f ? 0.f : h2m[c] * 0.1f) + dot[c] + b2r[c];
        h2m[c] = v;
        h2s[c] = (v > 0.5f) ? 1.f : 0.f;
        sum2[c] += h2s[c];
      }

#pragma unroll
      for (int rr = 0; rr < 13; ++rr) cur[rr] = nxt[rr];
    }

    if (L == 0) {
#pragma unroll
      for (int c = 0; c < NCLS; ++c) out[b * NCLS + c] = sum2[c] / bgt;
    }
    return;
  }

  // ---------------- PASTE role ----------------
  {
    int tid = (bxg - PASTE_BASE) * BLK + t;
    const int stride = RPASTE * BLK;
    for (int i = tid; i < TOTQ; i += stride) {
      int q  = i % 75;
      int rd = i / 75;
      int bb = rd / D_IN;
      int d  = rd - bb * D_IN;
      int ib = idx[bb];
      const float* ip = inp + (size_t)bb * (D_IN * WIN) + (size_t)d * WIN;
      int t0 = q * 4;
      float v[4];
#pragma unroll
      for (int e = 0; e < 4; ++e) {
        unsigned w = (unsigned)(t0 + e - ib);
        v[e] = (w < (unsigned)WIN) ? ip[w] : 0.f;
      }
      *(float4*)&outX[(size_t)rd * TSTEPS + t0] = make_float4(v[0], v[1], v[2], v[3]);
    }
  }
}

// ===========================================================================
// Fallback path (ws too small for flags): exact R12 two-kernel structure.
// ===========================================================================
__global__ __launch_bounds__(BLK) void gemm_kernel(
    const float* __restrict__ inp, const float* __restrict__ W1,
    float* __restrict__ P)
{
  __shared__ float As[BKK][MT];
  __shared__ float Bs[BKK][NT + 4];

  int t = threadIdx.x;
  int bx0 = blockIdx.x;
  int xcd = bx0 & 7;
  int jj  = bx0 >> 3;
  const int q8 = GEMM_BLOCKS >> 3;
  const int r8 = GEMM_BLOCKS & 7;
  int bx = (xcd < r8 ? xcd * (q8 + 1) : r8 * (q8 + 1) + (xcd - r8) * q8) + jj;

  int mt = bx / NTN;
  int nt = bx - mt * NTN;
  int m0 = mt * MT, n0 = nt * NT;

  int am = t & 63;
  int ah = t >> 6;
  int r  = m0 + am;
  int bb = r / 50, ss = r - bb * 50;
  const float* aptr = inp + (size_t)bb * (D_IN * WIN) + ss;

  int bn = t >> 4;
  int bk = t & 15;
  int l  = t & 63;
  int lm = l & 7;
  int ln = l >> 3;
  int tm = ah * 32 + lm * 4;
  int tn = ln * 4;

  float aN[8], bN[4];
#pragma unroll
  for (int q = 0; q < 8; ++q) aN[q] = aptr[(ah * 8 + q) * WIN];
#pragma unroll
  for (int p = 0; p < 4; ++p)
    bN[p] = W1[(size_t)(n0 + bn + 8 * p) * D_IN + bk];

  float acc[4][4] = {};

  for (int k0 = 0; k0 < D_IN; k0 += BKK) {
#pragma unroll
    for (int q = 0; q < 8; ++q) As[ah * 8 + q][am] = aN[q];
#pragma unroll
    for (int p = 0; p < 4; ++p) Bs[bk][bn + 8 * p] = bN[p];
    __syncthreads();

    int kn0 = k0 + BKK;
    if (kn0 + BKK <= D_IN) {
#pragma unroll
      for (int q = 0; q < 8; ++q) aN[q] = aptr[(kn0 + ah * 8 + q) * WIN];
#pragma unroll
      for (int p = 0; p < 4; ++p)
        bN[p] = W1[(size_t)(n0 + bn + 8 * p) * D_IN + kn0 + bk];
    } else if (kn0 < D_IN) {
#pragma unroll
      for (int q = 0; q < 8; ++q) {
        int kk = kn0 + ah * 8 + q;
        aN[q] = (kk < D_IN) ? aptr[kk * WIN] : 0.f;
      }
#pragma unroll
      for (int p = 0; p < 4; ++p) {
        int kk = kn0 + bk;
        bN[p] = (kk < D_IN) ? W1[(size_t)(n0 + bn + 8 * p) * D_IN + kk] : 0.f;
      }
    }

#pragma unroll
    for (int kk = 0; kk < BKK; ++kk) {
      float4 A0 = *(const float4*)&As[kk][tm];
      float4 B0 = *(const float4*)&Bs[kk][tn];
      float av[4] = {A0.x, A0.y, A0.z, A0.w};
      float bv[4] = {B0.x, B0.y, B0.z, B0.w};
#pragma unroll
      for (int i = 0; i < 4; ++i)
#pragma unroll
        for (int j = 0; j < 4; ++j)
          acc[i][j] += av[i] * bv[j];
    }
    __syncthreads();
  }

#pragma unroll
  for (int i = 0; i < 4; ++i) {
    int row = m0 + tm + i;
    *(float4*)&P[(size_t)row * HID + n0 + tn] =
        make_float4(acc[i][0], acc[i][1], acc[i][2], acc[i][3]);
  }
}

__global__ __launch_bounds__(64, 1) void recur_kernel(
    const float* __restrict__ P, const float* __restrict__ W2,
    const float* __restrict__ b2, const float* __restrict__ Wc,
    const float* __restrict__ bc, const float* __restrict__ b1,
    const int* __restrict__ idx, float* __restrict__ out,
    const float* __restrict__ inp, float* __restrict__ outX)
{
  int L = threadIdx.x;
  int b = blockIdx.x;

  if (b >= BATCH) {
    int tid = (b - BATCH) * 64 + L;
    const int stride = 1920 * 64;
    for (int i = tid; i < TOTQ; i += stride) {
      int q  = i % 75;
      int rd = i / 75;
      int bb = rd / D_IN;
      int d  = rd - bb * D_IN;
      int ib = idx[bb];
      const float* ip = inp + (size_t)bb * (D_IN * WIN) + (size_t)d * WIN;
      int t0 = q * 4;
      float v[4];
#pragma unroll
      for (int e = 0; e < 4; ++e) {
        unsigned w = (unsigned)(t0 + e - ib);
        v[e] = (w < (unsigned)WIN) ? ip[w] : 0.f;
      }
      *(float4*)&outX[(size_t)rd * TSTEPS + t0] = make_float4(v[0], v[1], v[2], v[3]);
    }
    return;
  }

  int myidx = idx[b];
  const float* Pb = P + (size_t)b * WIN * HID;

  float m[13], b1r[13], wcr[13];
  float w2r[NCLS][13];
  unsigned smask = 0;
#pragma unroll
  for (int rr = 0; rr < 13; ++rr) {
    int j = L + 64 * rr;
    bool ok = (j < HID);
    m[rr]   = 0.f;
    b1r[rr] = ok ? b1[j] : 0.f;
    wcr[rr] = ok ? Wc[j] : 0.f;
#pragma unroll
    for (int c = 0; c < NCLS; ++c)
      w2r[c][rr] = ok ? W2[c * HID + j] : 0.f;
  }

  float cm = 0.f, cs = 0.f, bgt = 1.f;
  float bc0 = bc[0];
  float wf0 = Wc[HID], wf1 = Wc[HID + 1], wf2 = Wc[HID + 2], wf3 = Wc[HID + 3];

  float h2m[10], h2s[10], sum2[10], b2r[10];
#pragma unroll
  for (int c = 0; c < NCLS; ++c) { h2m[c] = 0.f; h2s[c] = 0.f; sum2[c] = 0.f; b2r[c] = b2[c]; }

  float cur[13];
  {
    unsigned w0 = (unsigned)(0 - myidx);
    if (w0 < (unsigned)WIN) {
      const float* Pr = Pb + (size_t)w0 * HID;
#pragma unroll
      for (int rr = 0; rr < 13; ++rr) {
        int j = L + 64 * rr;
        cur[rr] = (j < HID) ? Pr[j] : 0.f;
      }
    } else {
#pragma unroll
      for (int rr = 0; rr < 13; ++rr) cur[rr] = 0.f;
    }
  }

  for (int step = 0; step < TSTEPS; ++step) {
    float gate = (step == 0) ? 1.f : cs;

    float nxt[13];
    {
      unsigned wn = (unsigned)(step + 1 - myidx);
      if (wn < (unsigned)WIN) {
        const float* Pr = Pb + (size_t)wn * HID;
#pragma unroll
        for (int rr = 0; rr < 13; ++rr) {
          int j = L + 64 * rr;
          nxt[rr] = (j < HID) ? Pr[j] : 0.f;
        }
      } else {
#pragma unroll
        for (int rr = 0; rr < 13; ++rr) nxt[rr] = 0.f;
      }
    }

    unsigned nmask = 0;
#pragma unroll
    for (int rr = 0; rr < 13; ++rr) {
      float mprev = ((smask >> rr) & 1u) ? 0.f : m[rr] * 0.1f;
      float mv = mprev + cur[rr] * gate + b1r[rr];
      m[rr] = mv;
      nmask |= (mv > 0.5f) ? (1u << rr) : 0u;
    }
    smask = nmask;

    unsigned long long ball = __ballot(smask != 0u);

    float ctrl = 0.f;
    float dot[10];
#pragma unroll
    for (int c = 0; c < NCLS; ++c) dot[c] = 0.f;

    if (ball) {
      float cacc = 0.f;
#pragma unroll
      for (int rr = 0; rr < 13; ++rr) {
        float f = (float)((smask >> rr) & 1u);
        cacc = fmaf(f, wcr[rr], cacc);
      }
      ctrl = wave_sum(cacc);

#pragma unroll
      for (int rr = 0; rr < 13; ++rr) {
        float f = (float)((smask >> rr) & 1u);
#pragma unroll
        for (int c = 0; c < NCLS; ++c)
          dot[c] = fmaf(f, w2r[c][rr], dot[c]);
      }
#pragma unroll
      for (int c = 0; c < NCLS; ++c) dot[c] = wave_sum(dot[c]);
    }

    bgt += (cs == 1.f) ? 1.f : 0.f;
    float fq = wf0;
    if ((step & 1) == 0)   fq += wf1;
    if (step % 10 == 0)    fq += wf2;
    if (step % 100 == 0)   fq += wf3;
    float cv = (cs != 0.f ? 0.f : cm * 0.1f) + ctrl + fq + bc0;
    cm = cv;
    cs = (cv > 0.5f) ? 1.f : 0.f;

#pragma unroll
    for (int c = 0; c < NCLS; ++c) {
      float v = (h2s[c] != 0.f ? 0.f : h2m[c] * 0.1f) + dot[c] + b2r[c];
      h2m[c] = v;
      h2s[c] = (v > 0.5f) ? 1.f : 0.f;
      sum2[c] += h2s[c];
    }

#pragma unroll
    for (int rr = 0; rr < 13; ++rr) cur[rr] = nxt[rr];
  }

  if (L == 0) {
#pragma unroll
    for (int c = 0; c < NCLS; ++c) out[b * NCLS + c] = sum2[c] / bgt;
  }
}

// ---------------------------------------------------------------------------
extern "C" void kernel_launch(void* const* d_in, const int* in_sizes, int n_in,
                              void* d_out, int out_size, void* d_ws, size_t ws_size,
                              hipStream_t stream) {
  const float* inp = (const float*)d_in[0];
  const int*   idx = (const int*)d_in[2];
  const float* W1  = (const float*)d_in[3];
  const float* b1  = (const float*)d_in[4];
  const float* W2  = (const float*)d_in[5];
  const float* b2  = (const float*)d_in[6];
  const float* Wc  = (const float*)d_in[7];
  const float* bc  = (const float*)d_in[8];

  float* out  = (float*)d_out;   // [0,1280): rate ; then X
  float* P    = (float*)d_ws;    // [6400][800] fp32 = 20.48 MB
  float* outX = out + BATCH * NCLS;

  if (ws_size >= (size_t)P_BYTES + NTM * sizeof(int)) {
    int* cnt = (int*)((char*)d_ws + P_BYTES);
    hipMemsetAsync(cnt, 0, NTM * sizeof(int), stream);
    fused_all<<<NB, BLK, 0, stream>>>(
        inp, W1, idx, P, W2, b2, Wc, bc, b1, out, outX, cnt);
  } else {
    // fallback: proven R12 two-kernel path
    gemm_kernel<<<GEMM_BLOCKS, BLK, 0, stream>>>(inp, W1, P);
    recur_kernel<<<BATCH + 1920, 64, 0, stream>>>(
        P, W2, b2, Wc, bc, b1, idx, out, inp, outX);
  }
}

// Round 15
// 1013.846 us; speedup vs baseline: 1.3152x; 1.3152x over previous
//
#include <hip/hip_runtime.h>

#define D_IN 2312
#define HID  800
#define NCLS 10
#define BATCH 128
#define TSTEPS 300
#define WIN  50

#define MT 64                              // block tile rows (2 waves x 32)
#define NT 32
#define BKK 16
#define NTM 100                            // 6400/64
#define NTN 25                             // 800/32, exact
#define GEMM_BLOCKS (NTM * NTN)            // 2500 two-wave tiles
#define BLK 128
#define RPASTE 1920                        // paste blocks appended to recur launch
#define TOTQ (BATCH * D_IN * (TSTEPS / 4)) // 22,195,200 float4s of X

// ---------------------------------------------------------------------------
// GEMM kernel — EXACT R12 version (best measured: 357 us, 48 VGPR, FETCH 181
// MB): R9 single-buffer 2-barrier structure + bijective XCD swizzle (each XCD
// owns a contiguous logical block range -> one m-tile group's 25 blocks share
// one L2; prefetch loads are ~200cy L2 hits hidden under the 512cy FMA phase).
// R14's single-kernel fusion regressed (VGPR 232 max-over-paths -> 10%
// occupancy); the two-kernel split is structurally required: gemm needs low
// VGPR/high TLP, recur needs high VGPR/low TLP.
// Per-output k-accumulation strictly sequential fmaf -> bit-identical P.
// ---------------------------------------------------------------------------
__global__ __launch_bounds__(BLK) void gemm_kernel(
    const float* __restrict__ inp,   // [B][D_IN][WIN]
    const float* __restrict__ W1,    // [HID][D_IN]
    float*       __restrict__ P)     // [6400][HID]
{
  __shared__ float As[BKK][MT];       // 4 KB
  __shared__ float Bs[BKK][NT + 4];   // 2.25 KB

  int t   = threadIdx.x;
  int bx0 = blockIdx.x;

  // bijective XCD swizzle: 2500 = 8*312 + 4 (validated R10/R11/R12)
  int xcd = bx0 & 7;
  int jj  = bx0 >> 3;
  const int q8 = GEMM_BLOCKS >> 3;      // 312
  const int r8 = GEMM_BLOCKS & 7;       // 4
  int bx = (xcd < r8 ? xcd * (q8 + 1) : r8 * (q8 + 1) + (xcd - r8) * q8) + jj;

  int mt = bx / NTN;                 // 25 consecutive logical blocks share m-tile
  int nt = bx - mt * NTN;
  int m0 = mt * MT, n0 = nt * NT;

  // A staging: 64 rows x 16 k staged by 128 threads (8 k's each),
  // coalesced along m (s-contiguous)
  int am = t & 63;
  int ah = t >> 6;                   // 0..1 -> k-half (== wave id)
  int r  = m0 + am;
  int bb = r / 50, ss = r - bb * 50;
  const float* aptr = inp + (size_t)bb * (D_IN * WIN) + ss;   // + k*WIN

  // B staging: 32 n x 16 k by 128 threads (4 each), coalesced along k
  int bn = t >> 4;                   // 0..7
  int bk = t & 15;                   // 0..15

  int l  = t & 63;
  int lm = l & 7;                    // m micro-group
  int ln = l >> 3;                   // n micro-group
  int tm = ah * 32 + lm * 4;         // wave ah owns rows [ah*32, ah*32+32)
  int tn = ln * 4;

  float aN[8], bN[4];
#pragma unroll
  for (int q = 0; q < 8; ++q) aN[q] = aptr[(ah * 8 + q) * WIN];
#pragma unroll
  for (int p = 0; p < 4; ++p)
    bN[p] = W1[(size_t)(n0 + bn + 8 * p) * D_IN + bk];

  float acc[4][4] = {};

  for (int k0 = 0; k0 < D_IN; k0 += BKK) {   // 145 slabs, last partial
#pragma unroll
    for (int q = 0; q < 8; ++q) As[ah * 8 + q][am] = aN[q];
#pragma unroll
    for (int p = 0; p < 4; ++p) Bs[bk][bn + 8 * p] = bN[p];
    __syncthreads();

    int kn0 = k0 + BKK;
    if (kn0 + BKK <= D_IN) {
      // next slab fully in range: guard-free prefetch (hot path, 143/145)
#pragma unroll
      for (int q = 0; q < 8; ++q) aN[q] = aptr[(kn0 + ah * 8 + q) * WIN];
#pragma unroll
      for (int p = 0; p < 4; ++p)
        bN[p] = W1[(size_t)(n0 + bn + 8 * p) * D_IN + kn0 + bk];
    } else if (kn0 < D_IN) {
      // next slab partial: guarded, zero-fill (adds exact 0s to acc)
#pragma unroll
      for (int q = 0; q < 8; ++q) {
        int kk = kn0 + ah * 8 + q;
        aN[q] = (kk < D_IN) ? aptr[kk * WIN] : 0.f;
      }
#pragma unroll
      for (int p = 0; p < 4; ++p) {
        int kk = kn0 + bk;
        bN[p] = (kk < D_IN) ? W1[(size_t)(n0 + bn + 8 * p) * D_IN + kk] : 0.f;
      }
    }

#pragma unroll
    for (int kk = 0; kk < BKK; ++kk) {
      float4 A0 = *(const float4*)&As[kk][tm];
      float4 B0 = *(const float4*)&Bs[kk][tn];
      float av[4] = {A0.x, A0.y, A0.z, A0.w};
      float bv[4] = {B0.x, B0.y, B0.z, B0.w};
#pragma unroll
      for (int i = 0; i < 4; ++i)
#pragma unroll
        for (int j = 0; j < 4; ++j)
          acc[i][j] += av[i] * bv[j];
    }
    __syncthreads();
  }

#pragma unroll
  for (int i = 0; i < 4; ++i) {
    int row = m0 + tm + i;
    *(float4*)&P[(size_t)row * HID + n0 + tn] =
        make_float4(acc[i][0], acc[i][1], acc[i][2], acc[i][3]);
  }
}

// ---------------------------------------------------------------------------
// DPP full-wave sum (proven round 6): VALU-speed cross-lane, no LDS pipe.
// ---------------------------------------------------------------------------
template <int CTRL>
__device__ __forceinline__ float dpp_add(float s) {
  return s + __int_as_float(__builtin_amdgcn_update_dpp(
      0, __float_as_int(s), CTRL, 0xf, 0xf, true));
}
__device__ __forceinline__ float wave_sum(float s) {
  s = dpp_add<0x111>(s);   // row_shr:1
  s = dpp_add<0x112>(s);   // row_shr:2
  s = dpp_add<0x114>(s);   // row_shr:4
  s = dpp_add<0x118>(s);   // row_shr:8   -> lane15 of each row = row sum
  s = dpp_add<0x142>(s);   // row_bcast:15 -> lane31 = r0+r1, lane63 = r2+r3
  s = dpp_add<0x143>(s);   // row_bcast:31 -> lane63 = total
  return __int_as_float(__builtin_amdgcn_readlane(__float_as_int(s), 63));
}

// ---------------------------------------------------------------------------
// Recurrence v7 — EXACT R12 version (best measured). W2/Wc/b1 in registers,
// DPP reductions, 1-step P prefetch; paste rides as blocks >= BATCH (proven
// ~free under the latency-bound recurrence).
// ---------------------------------------------------------------------------
__global__ __launch_bounds__(64, 1) void recur_kernel(
    const float* __restrict__ P,    // [6400][HID]
    const float* __restrict__ W2,   // [NCLS][HID]
    const float* __restrict__ b2,   // [NCLS]
    const float* __restrict__ Wc,   // [HID+4]
    const float* __restrict__ bc,   // [1]
    const float* __restrict__ b1,   // [HID]
    const int*   __restrict__ idx,  // [B]
    float*       __restrict__ out,  // [B][NCLS]
    const float* __restrict__ inp,  // [B][D_IN][WIN]  (paste)
    float*       __restrict__ outX) // [B][D_IN][T]    (paste)
{
  int L = threadIdx.x;
  int b = blockIdx.x;

  if (b >= BATCH) {
    // ---- paste path: X = zeros with input window pasted at idx[b] ----
    int tid = (b - BATCH) * 64 + L;
    const int stride = RPASTE * 64;
    for (int i = tid; i < TOTQ; i += stride) {
      int q  = i % 75;
      int rd = i / 75;
      int bb = rd / D_IN;
      int d  = rd - bb * D_IN;
      int ib = idx[bb];
      const float* ip = inp + (size_t)bb * (D_IN * WIN) + (size_t)d * WIN;
      int t0 = q * 4;
      float v[4];
#pragma unroll
      for (int e = 0; e < 4; ++e) {
        unsigned w = (unsigned)(t0 + e - ib);
        v[e] = (w < (unsigned)WIN) ? ip[w] : 0.f;
      }
      *(float4*)&outX[(size_t)rd * TSTEPS + t0] = make_float4(v[0], v[1], v[2], v[3]);
    }
    return;
  }

  int myidx = idx[b];
  const float* Pb = P + (size_t)b * WIN * HID;

  float m[13], b1r[13], wcr[13];
  float w2r[NCLS][13];
  unsigned smask = 0;
#pragma unroll
  for (int rr = 0; rr < 13; ++rr) {
    int j = L + 64 * rr;
    bool ok = (j < HID);
    m[rr]   = 0.f;
    b1r[rr] = ok ? b1[j] : 0.f;
    wcr[rr] = ok ? Wc[j] : 0.f;
#pragma unroll
    for (int c = 0; c < NCLS; ++c)
      w2r[c][rr] = ok ? W2[c * HID + j] : 0.f;
  }

  float cm = 0.f, cs = 0.f, bgt = 1.f;
  float bc0 = bc[0];
  float wf0 = Wc[HID], wf1 = Wc[HID + 1], wf2 = Wc[HID + 2], wf3 = Wc[HID + 3];

  float h2m[10], h2s[10], sum2[10], b2r[10];
#pragma unroll
  for (int c = 0; c < NCLS; ++c) { h2m[c] = 0.f; h2s[c] = 0.f; sum2[c] = 0.f; b2r[c] = b2[c]; }

  // prefetch P row for step 0
  float cur[13];
  {
    unsigned w0 = (unsigned)(0 - myidx);
    if (w0 < (unsigned)WIN) {
      const float* Pr = Pb + (size_t)w0 * HID;
#pragma unroll
      for (int rr = 0; rr < 13; ++rr) {
        int j = L + 64 * rr;
        cur[rr] = (j < HID) ? Pr[j] : 0.f;
      }
    } else {
#pragma unroll
      for (int rr = 0; rr < 13; ++rr) cur[rr] = 0.f;
    }
  }

  for (int step = 0; step < TSTEPS; ++step) {
    float gate = (step == 0) ? 1.f : cs;

    // unconditional prefetch of next step's P row (independent of this
    // step's chain; gating is applied at use as *gate, exact for {0,1})
    float nxt[13];
    {
      unsigned wn = (unsigned)(step + 1 - myidx);
      if (wn < (unsigned)WIN) {
        const float* Pr = Pb + (size_t)wn * HID;
#pragma unroll
        for (int rr = 0; rr < 13; ++rr) {
          int j = L + 64 * rr;
          nxt[rr] = (j < HID) ? Pr[j] : 0.f;
        }
      } else {
#pragma unroll
        for (int rr = 0; rr < 13; ++rr) nxt[rr] = 0.f;
      }
    }

    unsigned nmask = 0;
#pragma unroll
    for (int rr = 0; rr < 13; ++rr) {
      float mprev = ((smask >> rr) & 1u) ? 0.f : m[rr] * 0.1f;
      float mv = mprev + cur[rr] * gate + b1r[rr];
      m[rr] = mv;
      nmask |= (mv > 0.5f) ? (1u << rr) : 0u;
    }
    smask = nmask;

    unsigned long long ball = __ballot(smask != 0u);

    float ctrl = 0.f;
    float dot[10];
#pragma unroll
    for (int c = 0; c < NCLS; ++c) dot[c] = 0.f;

    if (ball) {
      // ctrl dot: branchless FMA over own units, DPP wave reduce
      float cacc = 0.f;
#pragma unroll
      for (int rr = 0; rr < 13; ++rr) {
        float f = (float)((smask >> rr) & 1u);
        cacc = fmaf(f, wcr[rr], cacc);
      }
      ctrl = wave_sum(cacc);

      // h2 dots: per-lane partials over own 13 units (all-register), then
      // DPP wave reduce x10
#pragma unroll
      for (int rr = 0; rr < 13; ++rr) {
        float f = (float)((smask >> rr) & 1u);
#pragma unroll
        for (int c = 0; c < NCLS; ++c)
          dot[c] = fmaf(f, w2r[c][rr], dot[c]);
      }
#pragma unroll
      for (int c = 0; c < NCLS; ++c) dot[c] = wave_sum(dot[c]);
    }

    // ctrl neuron + budget (uses prev-step cs, then updates it)
    bgt += (cs == 1.f) ? 1.f : 0.f;
    float fq = wf0;
    if ((step & 1) == 0)   fq += wf1;
    if (step % 10 == 0)    fq += wf2;
    if (step % 100 == 0)   fq += wf3;
    float cv = (cs != 0.f ? 0.f : cm * 0.1f) + ctrl + fq + bc0;
    cm = cv;
    cs = (cv > 0.5f) ? 1.f : 0.f;

    // h2 membrane update every step (dot==0 on silent steps)
#pragma unroll
    for (int c = 0; c < NCLS; ++c) {
      float v = (h2s[c] != 0.f ? 0.f : h2m[c] * 0.1f) + dot[c] + b2r[c];
      h2m[c] = v;
      h2s[c] = (v > 0.5f) ? 1.f : 0.f;
      sum2[c] += h2s[c];
    }

#pragma unroll
    for (int rr = 0; rr < 13; ++rr) cur[rr] = nxt[rr];
  }

  if (L == 0) {
#pragma unroll
    for (int c = 0; c < NCLS; ++c) out[b * NCLS + c] = sum2[c] / bgt;
  }
}

// ---------------------------------------------------------------------------
extern "C" void kernel_launch(void* const* d_in, const int* in_sizes, int n_in,
                              void* d_out, int out_size, void* d_ws, size_t ws_size,
                              hipStream_t stream) {
  const float* inp = (const float*)d_in[0];
  const int*   idx = (const int*)d_in[2];
  const float* W1  = (const float*)d_in[3];
  const float* b1  = (const float*)d_in[4];
  const float* W2  = (const float*)d_in[5];
  const float* b2  = (const float*)d_in[6];
  const float* Wc  = (const float*)d_in[7];
  const float* bc  = (const float*)d_in[8];

  float* out = (float*)d_out;   // [0,1280): rate ; then X
  float* P   = (float*)d_ws;    // [6400][800] fp32 = 20.48 MB

  gemm_kernel<<<GEMM_BLOCKS, BLK, 0, stream>>>(inp, W1, P);

  recur_kernel<<<BATCH + RPASTE, 64, 0, stream>>>(
      P, W2, b2, Wc, bc, b1, idx, out, inp, out + BATCH * NCLS);
}